// Round 2
// baseline (2501.318 us; speedup 1.0000x reference)
//
#include <hip/hip_runtime.h>

#define B_    512
#define T_    256
#define D_    64
#define H_    8
#define E_    8
#define HID_  2048
#define EPS_  1e-5f
#define SCALE_ 0.3535533905932738f  // 1/sqrt(8)

// ---------------- Kernel A: per-(b,h) QKV + causal online-softmax attention ----------------
__global__ __launch_bounds__(256) void attn_k(
    const float* __restrict__ x,
    const float* __restrict__ Wq, const float* __restrict__ bq,
    const float* __restrict__ Wk, const float* __restrict__ bk,
    const float* __restrict__ Wv, const float* __restrict__ bv,
    float* __restrict__ o_ws)
{
  __shared__ __align__(16) float xs[64][68];            // 64-token x chunk, pad 68
  __shared__ __align__(16) float qs[256][8], ks[256][8], vs[256][8];
  __shared__ __align__(16) float wqs[512], wks[512], wvs[512];  // [d][e] flat
  __shared__ float bqs[8], bks[8], bvs[8];

  const int tid = threadIdx.x;
  const int b = blockIdx.x >> 3, h = blockIdx.x & 7;

  // stage per-head weights (64x8 each)
  for (int i = tid; i < 512; i += 256) {
    wqs[i] = Wq[h * 512 + i];
    wks[i] = Wk[h * 512 + i];
    wvs[i] = Wv[h * 512 + i];
  }
  if (tid < 8) {
    bqs[tid] = bq[h * 8 + tid];
    bks[tid] = bk[h * 8 + tid];
    bvs[tid] = bv[h * 8 + tid];
  }

  // QKV in 4 chunks of 64 tokens
  const int e = tid & 7, tg = tid >> 3;
  for (int ch = 0; ch < 4; ++ch) {
    {
      const int r = tid >> 2, cq = tid & 3;
      const float* xrow = x + ((size_t)b * T_ + ch * 64 + r) * D_ + cq * 16;
      float* dst = &xs[r][cq * 16];
      #pragma unroll
      for (int c = 0; c < 4; ++c)
        *(float4*)&dst[c * 4] = *(const float4*)&xrow[c * 4];
    }
    __syncthreads();
    #pragma unroll
    for (int i = 0; i < 2; ++i) {
      const int tl = tg + 32 * i, t = ch * 64 + tl;
      float aq = bqs[e], ak = bks[e], av = bvs[e];
      #pragma unroll
      for (int c = 0; c < 16; ++c) {
        float4 xv = *(const float4*)&xs[tl][c * 4];
        const int d = c * 4;
        aq += xv.x * wqs[(d + 0) * 8 + e] + xv.y * wqs[(d + 1) * 8 + e]
            + xv.z * wqs[(d + 2) * 8 + e] + xv.w * wqs[(d + 3) * 8 + e];
        ak += xv.x * wks[(d + 0) * 8 + e] + xv.y * wks[(d + 1) * 8 + e]
            + xv.z * wks[(d + 2) * 8 + e] + xv.w * wks[(d + 3) * 8 + e];
        av += xv.x * wvs[(d + 0) * 8 + e] + xv.y * wvs[(d + 1) * 8 + e]
            + xv.z * wvs[(d + 2) * 8 + e] + xv.w * wvs[(d + 3) * 8 + e];
      }
      qs[t][e] = aq * SCALE_;
      ks[t][e] = ak;
      vs[t][e] = av;
    }
    __syncthreads();
  }

  // attention: thread t = tid owns query row t, online softmax over s<=t
  {
    const int t = tid;
    float4 q0 = *(const float4*)&qs[t][0];
    float4 q1 = *(const float4*)&qs[t][4];
    float m = -INFINITY, l = 0.f;
    float o0 = 0, o1 = 0, o2 = 0, o3 = 0, o4 = 0, o5 = 0, o6 = 0, o7 = 0;
    for (int s = 0; s <= t; ++s) {     // all active lanes read same s -> LDS broadcast
      float4 ka = *(const float4*)&ks[s][0];
      float4 kb = *(const float4*)&ks[s][4];
      float sc = q0.x * ka.x + q0.y * ka.y + q0.z * ka.z + q0.w * ka.w
               + q1.x * kb.x + q1.y * kb.y + q1.z * kb.z + q1.w * kb.w;
      float mn = fmaxf(m, sc);
      float corr = __expf(m - mn);     // first iter: exp(-inf)=0
      float p = __expf(sc - mn);
      m = mn;
      l = l * corr + p;
      float4 va = *(const float4*)&vs[s][0];
      float4 vb = *(const float4*)&vs[s][4];
      o0 = o0 * corr + p * va.x;  o1 = o1 * corr + p * va.y;
      o2 = o2 * corr + p * va.z;  o3 = o3 * corr + p * va.w;
      o4 = o4 * corr + p * vb.x;  o5 = o5 * corr + p * vb.y;
      o6 = o6 * corr + p * vb.z;  o7 = o7 * corr + p * vb.w;
    }
    float inv = 1.f / l;
    float* orow = o_ws + ((size_t)b * T_ + t) * D_ + h * E_;
    float4 r0 = { o0 * inv, o1 * inv, o2 * inv, o3 * inv };
    float4 r1 = { o4 * inv, o5 * inv, o6 * inv, o7 * inv };
    *(float4*)&orow[0] = r0;
    *(float4*)&orow[4] = r1;
  }
}

// ---------------- Kernel B: output proj + residual + LN1 (32 tokens / WG) ----------------
__global__ __launch_bounds__(256) void proj_ln1_k(
    const float* __restrict__ x,
    const float* __restrict__ Wp, const float* __restrict__ bp,
    const float* __restrict__ g1, const float* __restrict__ be1,
    const float* __restrict__ o_ws, float* __restrict__ h_ws)
{
  __shared__ __align__(16) float os[32][68];   // pad 68
  __shared__ __align__(16) float wps[4096];    // Wp [i][d] flat
  const int tid = threadIdx.x;
  const size_t t0 = (size_t)blockIdx.x * 32;

  {
    const int t = tid >> 3, c = tid & 7;
    const float* orow = o_ws + (t0 + t) * D_ + c * 8;
    *(float4*)&os[t][c * 8 + 0] = *(const float4*)&orow[0];
    *(float4*)&os[t][c * 8 + 4] = *(const float4*)&orow[4];
  }
  #pragma unroll
  for (int c = 0; c < 4; ++c)
    ((float4*)wps)[tid + 256 * c] = ((const float4*)Wp)[tid + 256 * c];
  __syncthreads();

  const int t = tid >> 3, tl = tid & 7, d0 = tl * 8;
  float acc[8];
  {
    float4 b0 = *(const float4*)&bp[d0];
    float4 b1v = *(const float4*)&bp[d0 + 4];
    acc[0] = b0.x; acc[1] = b0.y; acc[2] = b0.z; acc[3] = b0.w;
    acc[4] = b1v.x; acc[5] = b1v.y; acc[6] = b1v.z; acc[7] = b1v.w;
  }
  for (int i = 0; i < 64; ++i) {
    float ov = os[t][i];
    const float* wr = &wps[i * 64 + d0];
    float4 w0 = *(const float4*)wr;
    float4 w1 = *(const float4*)(wr + 4);
    acc[0] += ov * w0.x; acc[1] += ov * w0.y; acc[2] += ov * w0.z; acc[3] += ov * w0.w;
    acc[4] += ov * w1.x; acc[5] += ov * w1.y; acc[6] += ov * w1.z; acc[7] += ov * w1.w;
  }
  // residual
  float r[8];
  {
    const float* xrow = x + (t0 + t) * D_ + d0;
    float4 x0 = *(const float4*)&xrow[0];
    float4 x1 = *(const float4*)&xrow[4];
    r[0] = x0.x + acc[0]; r[1] = x0.y + acc[1]; r[2] = x0.z + acc[2]; r[3] = x0.w + acc[3];
    r[4] = x1.x + acc[4]; r[5] = x1.y + acc[5]; r[6] = x1.z + acc[6]; r[7] = x1.w + acc[7];
  }
  float s1 = 0.f, s2 = 0.f;
  #pragma unroll
  for (int k = 0; k < 8; ++k) { s1 += r[k]; s2 += r[k] * r[k]; }
  #pragma unroll
  for (int mM = 1; mM < 8; mM <<= 1) {
    s1 += __shfl_xor(s1, mM, 8);
    s2 += __shfl_xor(s2, mM, 8);
  }
  float mu = s1 * (1.f / 64.f);
  float var = s2 * (1.f / 64.f) - mu * mu;
  float rstd = rsqrtf(var + EPS_);
  float4 g0 = *(const float4*)&g1[d0];
  float4 g1v = *(const float4*)&g1[d0 + 4];
  float4 e0 = *(const float4*)&be1[d0];
  float4 e1 = *(const float4*)&be1[d0 + 4];
  float4 h0, h1;
  h0.x = (r[0] - mu) * rstd * g0.x + e0.x;
  h0.y = (r[1] - mu) * rstd * g0.y + e0.y;
  h0.z = (r[2] - mu) * rstd * g0.z + e0.z;
  h0.w = (r[3] - mu) * rstd * g0.w + e0.w;
  h1.x = (r[4] - mu) * rstd * g1v.x + e1.x;
  h1.y = (r[5] - mu) * rstd * g1v.y + e1.y;
  h1.z = (r[6] - mu) * rstd * g1v.z + e1.z;
  h1.w = (r[7] - mu) * rstd * g1v.w + e1.w;
  float* hrow = h_ws + (t0 + t) * D_ + d0;
  *(float4*)&hrow[0] = h0;
  *(float4*)&hrow[4] = h1;
}

// ---------------- Kernel C: FFN (64->2048->64) + residual + LN2 (16 tokens / WG) ----------------
__global__ __launch_bounds__(256) void ffn_ln2_k(
    const float* __restrict__ W1, const float* __restrict__ b1,
    const float* __restrict__ W2, const float* __restrict__ b2,
    const float* __restrict__ g2, const float* __restrict__ be2,
    const float* __restrict__ h_ws, float* __restrict__ out)
{
  __shared__ __align__(16) float hs[16][68];    // h tile, pad 68
  __shared__ __align__(16) float hid[16][264];  // hidden chunk, pad 264
  const int tid = threadIdx.x;
  const size_t t0 = (size_t)blockIdx.x * 16;

  {
    const int t = tid >> 4, c = tid & 15;
    *(float4*)&hs[t][c * 4] = *(const float4*)&h_ws[(t0 + t) * D_ + c * 4];
  }
  __syncthreads();

  const int tt = tid >> 4, dg = tid & 15, d0 = dg * 4;
  float accO[4] = { 0.f, 0.f, 0.f, 0.f };

  for (int ch = 0; ch < 8; ++ch) {
    const int c0 = ch * 256;
    // phase 1: thread owns hidden column j = c0 + tid for all 16 tokens
    {
      const int j = c0 + tid;
      float acc[16];
      #pragma unroll
      for (int t = 0; t < 16; ++t) acc[t] = 0.f;
      for (int d4 = 0; d4 < 64; d4 += 4) {
        float w0 = W1[(size_t)(d4 + 0) * HID_ + j];
        float w1 = W1[(size_t)(d4 + 1) * HID_ + j];
        float w2v = W1[(size_t)(d4 + 2) * HID_ + j];
        float w3 = W1[(size_t)(d4 + 3) * HID_ + j];
        #pragma unroll
        for (int t = 0; t < 16; ++t) {
          float4 h4 = *(const float4*)&hs[t][d4];
          acc[t] += h4.x * w0 + h4.y * w1 + h4.z * w2v + h4.w * w3;
        }
      }
      float bj = b1[j];
      #pragma unroll
      for (int t = 0; t < 16; ++t) hid[t][tid] = fmaxf(acc[t] + bj, 0.f);
    }
    __syncthreads();
    // phase 2: thread (tt, dg) accumulates out dims d0..d0+3 over this chunk
    #pragma unroll 4
    for (int j = 0; j < 256; ++j) {
      float hv = hid[tt][j];
      float4 w4 = *(const float4*)&W2[(size_t)(c0 + j) * D_ + d0];
      accO[0] += hv * w4.x;
      accO[1] += hv * w4.y;
      accO[2] += hv * w4.z;
      accO[3] += hv * w4.w;
    }
    __syncthreads();
  }

  // epilogue: bias, residual, LN2 over 16 lanes (token tt), store
  float4 b2r = *(const float4*)&b2[d0];
  float r[4];
  r[0] = hs[tt][d0 + 0] + accO[0] + b2r.x;
  r[1] = hs[tt][d0 + 1] + accO[1] + b2r.y;
  r[2] = hs[tt][d0 + 2] + accO[2] + b2r.z;
  r[3] = hs[tt][d0 + 3] + accO[3] + b2r.w;
  float s1 = r[0] + r[1] + r[2] + r[3];
  float s2 = r[0] * r[0] + r[1] * r[1] + r[2] * r[2] + r[3] * r[3];
  #pragma unroll
  for (int mM = 1; mM < 16; mM <<= 1) {
    s1 += __shfl_xor(s1, mM, 16);
    s2 += __shfl_xor(s2, mM, 16);
  }
  float mu = s1 * (1.f / 64.f);
  float var = s2 * (1.f / 64.f) - mu * mu;
  float rstd = rsqrtf(var + EPS_);
  float4 g2r = *(const float4*)&g2[d0];
  float4 e2r = *(const float4*)&be2[d0];
  float4 o4;
  o4.x = (r[0] - mu) * rstd * g2r.x + e2r.x;
  o4.y = (r[1] - mu) * rstd * g2r.y + e2r.y;
  o4.z = (r[2] - mu) * rstd * g2r.z + e2r.z;
  o4.w = (r[3] - mu) * rstd * g2r.w + e2r.w;
  *(float4*)&out[(t0 + tt) * D_ + d0] = o4;
}

extern "C" void kernel_launch(void* const* d_in, const int* in_sizes, int n_in,
                              void* d_out, int out_size, void* d_ws, size_t ws_size,
                              hipStream_t stream) {
  const float* x   = (const float*)d_in[0];
  const float* Wq  = (const float*)d_in[1];
  const float* bq  = (const float*)d_in[2];
  const float* Wk  = (const float*)d_in[3];
  const float* bk  = (const float*)d_in[4];
  const float* Wv  = (const float*)d_in[5];
  const float* bv  = (const float*)d_in[6];
  const float* Wp  = (const float*)d_in[7];
  const float* bp  = (const float*)d_in[8];
  const float* g1  = (const float*)d_in[9];
  const float* be1 = (const float*)d_in[10];
  const float* W1  = (const float*)d_in[11];
  const float* b1  = (const float*)d_in[12];
  const float* W2  = (const float*)d_in[13];
  const float* b2  = (const float*)d_in[14];
  const float* g2  = (const float*)d_in[15];
  const float* be2 = (const float*)d_in[16];
  float* out = (float*)d_out;

  float* o_ws = (float*)d_ws;                            // [B*T*64] fp32 attn output (heads concat)
  float* h_ws = o_ws + (size_t)B_ * T_ * D_;             // [B*T*64] fp32 post-LN1

  attn_k<<<B_ * H_, 256, 0, stream>>>(x, Wq, bq, Wk, bk, Wv, bv, o_ws);
  proj_ln1_k<<<(B_ * T_) / 32, 256, 0, stream>>>(x, Wp, bp, g1, be1, o_ws, h_ws);
  ffn_ln2_k<<<(B_ * T_) / 16, 256, 0, stream>>>(W1, b1, W2, b2, g2, be2, h_ws, out);
}